// Round 12
// baseline (818.969 us; speedup 1.0000x reference)
//
// Round 12: R9 4-phase skeleton + 32x32x16 MFMA (half the MFMA instruction count,
// R5-verified fragment/epilogue math). 256² tile back (R11 reverted). fc2 split-K=2.
#include <hip/hip_runtime.h>
#include <stdint.h>

#define BATCH 256
#define SEQ   80
#define DIM   1024
#define HEADS 8
#define HDIM  128
#define HID   4096
#define NTOK  (BATCH * SEQ)   // 20480

typedef unsigned short u16;
using short8_t = __attribute__((ext_vector_type(8))) short;   // 8 bf16 (4 VGPRs)
using f32x4    = __attribute__((ext_vector_type(4))) float;
using f32x16   = __attribute__((ext_vector_type(16))) float;

__device__ __forceinline__ u16 f2bf(float f) {
  unsigned u = __float_as_uint(f);
  u += 0x7fffu + ((u >> 16) & 1u);   // RNE; inputs are finite
  return (u16)(u >> 16);
}
__device__ __forceinline__ float bf2f(u16 u) {
  return __uint_as_float(((unsigned)u) << 16);
}

__device__ __forceinline__ float gelu_exact(float v) {
  return 0.5f * v * (1.0f + erff(v * 0.70710678118654752f));
}

// async global->LDS, 16B per lane; lds dest = base + lane*16 (base wave-uniform)
#define GLD16(gp, lp)                                                   \
  __builtin_amdgcn_global_load_lds(                                     \
      (__attribute__((address_space(1))) void*)(void*)(gp),             \
      (__attribute__((address_space(3))) void*)(void*)(lp), 16, 0, 0)

// ---------------------------------------------------------------- casts
__global__ __launch_bounds__(256) void cast_bf16_kernel(
    const float* __restrict__ in, u16* __restrict__ out, int n4) {
  int i = blockIdx.x * 256 + threadIdx.x;
  int stride = gridDim.x * 256;
  for (; i < n4; i += stride) {
    float4 v = ((const float4*)in)[i];
    uint2 o;
    o.x = (unsigned)f2bf(v.x) | ((unsigned)f2bf(v.y) << 16);
    o.y = (unsigned)f2bf(v.z) | ((unsigned)f2bf(v.w) << 16);
    ((uint2*)out)[i] = o;
  }
}

// in: R x C fp32 row-major -> out: C x R bf16 row-major  (R,C multiples of 32)
__global__ __launch_bounds__(256) void transpose_cast_kernel(
    const float* __restrict__ in, u16* __restrict__ out, int R, int C) {
  __shared__ float tile[32][33];
  int c0 = blockIdx.x * 32, r0 = blockIdx.y * 32;
  for (int k = 0; k < 4; k++) {
    int i = threadIdx.y + k * 8;
    tile[i][threadIdx.x] = in[(size_t)(r0 + i) * C + c0 + threadIdx.x];
  }
  __syncthreads();
  for (int k = 0; k < 4; k++) {
    int i = threadIdx.y + k * 8;
    out[(size_t)(c0 + i) * R + r0 + threadIdx.x] = f2bf(tile[threadIdx.x][i]);
  }
}

// ---------------------------------------------------------------- 4-phase GEMM, 32x32x16
// C[M,N] = A[M,Ks] * Bt[N,Ks]^T, bf16 out. 256x256 tile, 8 waves (2Mx4N), per-wave
// 128x64 = acc[4][2] of 32x32 frags (f32x16), mfma_f32_32x32x16_bf16.
// 2 tiles (BK=64, k-halved) per iter, 4 phases/iter, 16 MFMA-instr per phase
// (vs 32 with 16x16 — issue-port relief; frag math verified in R5).
// LDS: 8 regions x 8192 u16 (region = buf*4 + mat*2 + kh, [256 rows][32 cols]).
// Phase q: {RD 12 frags of (buf,kh)=q; STG 2 regions (4 GLD); vm(8); barrier;
//           lgkmcnt(0); setprio(1); 16 MFMA; setprio(0)}.
// Stages: q0:(1,1)@t1-current, q1:(0,0)@t0+2, q2:(0,1)@t0+2, q3:(1,0)@t1+2.
// Ledger: 4 loads/phase FIFO; uniform vm(8) retires exactly the region read next
// phase; WAR holds (re-stage after the barrier following its last reader's issue).
// Peeled last iter: vm(8)@q0, vm(4)@q1, vm(0)@q2.  (R9's ledger, unchanged.)
// Split-K: kp = swz/(ntn*ntm) -> outp/outp1. EPI: 0 plain; 1 +bias GELU; 2 +bias.
// Keff % 128 == 0.
template <int EPI>
__global__ __launch_bounds__(512, 2) void gemm4q(
    const u16* __restrict__ A, const u16* __restrict__ Bt,
    const float* __restrict__ bias, u16* __restrict__ outp, u16* __restrict__ outp1,
    int M, int N, int Keff, int Ks, int ntn, int ntm) {
  __shared__ __align__(16) u16 lds[65536];   // 8 x 8192 u16 = 128 KiB

  const int tid = threadIdx.x;
  const int lane = tid & 63, wave = tid >> 6;
  const int wm = wave >> 2, wn = wave & 3;
  const int l31 = lane & 31, khalf = lane >> 5;

  // bijective XCD swizzle (m204 variant)
  const int nwg = gridDim.x;
  int q8 = nwg >> 3, r8 = nwg & 7;
  int xcd = blockIdx.x & 7, off = blockIdx.x >> 3;
  int swz = (xcd < r8 ? xcd * (q8 + 1) : r8 * (q8 + 1) + (xcd - r8) * q8) + off;
  const int per = ntn * ntm;
  const int kp = swz / per, rem = swz % per;
  const int bn = rem % ntn, bm = rem / ntn;
  const size_t arow0 = (size_t)bm * 256, bcol0 = (size_t)bn * 256;
  const int kbase = kp * Keff;

  // staging: thread covers granules {tid, 512+tid} of each region (1024 x 16B).
  const int srow = tid >> 2;
  const int slb  = (tid & 3) ^ ((srow >> 1) & 3);
  const u16* sA = A + (arow0 + srow) * (size_t)Ks + kbase + slb * 8;
  const u16* sB = Bt + (bcol0 + srow) * (size_t)Ks + kbase + slb * 8;
  const size_t sstep = 128 * (size_t)Ks;

  // 32x32 frag read bases (u16, R5-verified): granule = (ks*2+khalf) ^ ((row>>1)&3);
  // ks=1 frag = base ^ 16 (holds since (2+khalf)^s == 2^(khalf^s)).
  const int ar0 = wm * 128 + l31;
  const int aoff = ar0 * 32 + ((khalf ^ ((ar0 >> 1) & 3)) << 3);
  const int br0 = wn * 64 + l31;
  const int boff = br0 * 32 + ((khalf ^ ((br0 >> 1) & 3)) << 3);

  f32x16 acc[4][2] = {};
  const int NT = Keff >> 6;   // BK=64 tiles
  const int NI = NT >> 1;     // iterations (2 tiles each)

#define STG(mat, buf, kh, t)                                                  \
  do {                                                                        \
    const u16* s_ = ((mat) ? sB : sA) + (size_t)(t) * 64 + (kh) * 32;         \
    u16* d_ = lds + ((((buf) << 2) | ((mat) << 1) | (kh)) << 13) + wave * 512;\
    GLD16(s_, d_);                                                            \
    GLD16(s_ + sstep, d_ + 4096);                                             \
  } while (0)

#define RD_A(buf, kh, dst)                                                    \
  _Pragma("unroll") for (int mi = 0; mi < 4; ++mi) {                          \
    dst[mi][0] = *(const short8_t*)&lds[((((buf) << 2) | (kh)) << 13) + aoff +\
                                        mi * 1024];                           \
    dst[mi][1] = *(const short8_t*)&lds[(((((buf) << 2) | (kh)) << 13) + aoff \
                                         + mi * 1024) ^ 16];                  \
  }

#define RD_B(buf, kh, dst)                                                    \
  _Pragma("unroll") for (int ni = 0; ni < 2; ++ni) {                          \
    dst[ni][0] = *(const short8_t*)&lds[((((buf) << 2) | 2 | (kh)) << 13) +   \
                                        boff + ni * 1024];                    \
    dst[ni][1] = *(const short8_t*)&lds[(((((buf) << 2) | 2 | (kh)) << 13) +  \
                                         boff + ni * 1024) ^ 16];             \
  }

#define MFMAQ(aR, bR)                                                         \
  __builtin_amdgcn_s_setprio(1);                                              \
  _Pragma("unroll") for (int ks = 0; ks < 2; ++ks)                            \
  _Pragma("unroll") for (int mi = 0; mi < 4; ++mi)                            \
  _Pragma("unroll") for (int ni = 0; ni < 2; ++ni)                            \
      acc[mi][ni] = __builtin_amdgcn_mfma_f32_32x32x16_bf16(                  \
          aR[mi][ks], bR[ni][ks], acc[mi][ni], 0, 0, 0);                      \
  __builtin_amdgcn_s_setprio(0);

#define BAR()   asm volatile("s_barrier" ::: "memory")
#define LGKM0() asm volatile("s_waitcnt lgkmcnt(0)" ::: "memory")

#define PHASE(buf, kh, aR, bR, STGCODE, VMASM)                                \
  do {                                                                        \
    RD_A(buf, kh, aR);                                                        \
    RD_B(buf, kh, bR);                                                        \
    STGCODE;                                                                  \
    asm volatile(VMASM ::: "memory");                                         \
    BAR();                                                                    \
    LGKM0();                                                                  \
    MFMAQ(aR, bR);                                                            \
  } while (0)

  // prologue: stage region-pairs (0,0)@t0, (0,1)@t0, (1,0)@t1  (12 GLD)
  STG(0, 0, 0, 0); STG(1, 0, 0, 0);
  STG(0, 0, 1, 0); STG(1, 0, 1, 0);
  STG(0, 1, 0, 1); STG(1, 1, 0, 1);
  asm volatile("s_waitcnt vmcnt(0)" ::: "memory");
  BAR();

  short8_t aX[4][2], bX[2][2], aY[4][2], bY[2][2];

  for (int i = 0; i < NI - 1; ++i) {
    const int t0 = 2 * i, t1 = 2 * i + 1;
    PHASE(0, 0, aX, bX, { STG(0, 1, 1, t1);     STG(1, 1, 1, t1); },
          "s_waitcnt vmcnt(8)");
    PHASE(0, 1, aY, bY, { STG(0, 0, 0, t0 + 2); STG(1, 0, 0, t0 + 2); },
          "s_waitcnt vmcnt(8)");
    PHASE(1, 0, aX, bX, { STG(0, 0, 1, t0 + 2); STG(1, 0, 1, t0 + 2); },
          "s_waitcnt vmcnt(8)");
    PHASE(1, 1, aY, bY, { STG(0, 1, 0, t1 + 2); STG(1, 1, 0, t1 + 2); },
          "s_waitcnt vmcnt(8)");
  }
  // peeled last iteration
  {
    const int t1 = NT - 1;
    PHASE(0, 0, aX, bX, { STG(0, 1, 1, t1); STG(1, 1, 1, t1); },
          "s_waitcnt vmcnt(8)");
    PHASE(0, 1, aY, bY, {}, "s_waitcnt vmcnt(4)");
    PHASE(1, 0, aX, bX, {}, "s_waitcnt vmcnt(0)");
    PHASE(1, 1, aY, bY, {}, "");
  }
#undef PHASE
#undef STG
#undef RD_A
#undef RD_B
#undef MFMAQ

  asm volatile("s_waitcnt vmcnt(0)" ::: "memory");
  __syncthreads();

  // epilogue (R5-verified 32x32 C/D mapping): acc -> LDS [256][256] u16 -> stores
  u16* ct = lds;
#pragma unroll
  for (int ni = 0; ni < 2; ++ni) {
    int col = wn * 64 + ni * 32 + l31;
    float bv = 0.f;
    if constexpr (EPI != 0) bv = bias[bcol0 + col];
#pragma unroll
    for (int mi = 0; mi < 4; ++mi) {
#pragma unroll
      for (int r = 0; r < 16; ++r) {
        int row = wm * 128 + mi * 32 + (r & 3) + ((r >> 2) << 3) + (khalf << 2);
        float v = acc[mi][ni][r] + bv;
        if constexpr (EPI == 1) v = gelu_exact(v);
        ct[row * 256 + col] = f2bf(v);
      }
    }
  }
  __syncthreads();
  u16* op = (kp ? outp1 : outp) + arow0 * (size_t)N + bcol0;
#pragma unroll
  for (int i = 0; i < 16; ++i) {
    int c = i * 512 + tid;
    int row = c >> 5, o2 = (c & 31) * 8;
    *(short8_t*)(op + (size_t)row * N + o2) = *(const short8_t*)&ct[row * 256 + o2];
  }
}

// ---------------------------------------------------------------- attention
// One wave per (local b, h). QKV chunk: [nb*80][3072] bf16 (Q|K|V, head h at h*128).
__global__ __launch_bounds__(64) void attn_kernel(
    const u16* __restrict__ QKV, const float* __restrict__ bias_table,
    u16* __restrict__ attnout) {
  __shared__ __align__(16) u16 Kt[80 * 128];   // [key][d]; reused as P [80][104]
  __shared__ __align__(16) u16 Vt[96 * 128];   // [key][d], rows 80..95 zeroed
  __shared__ float bias_l[159];

  const int bh = blockIdx.x;
  const int b = bh >> 3, h = bh & 7;
  const int lane = threadIdx.x, lo = lane & 15, hi = lane >> 4;
  const size_t tokbase = (size_t)b * SEQ * 3072;
  const u16* Qg = QKV + tokbase + h * HDIM;
  const u16* Kg = QKV + tokbase + 1024 + h * HDIM;
  const u16* Vg = QKV + tokbase + 2048 + h * HDIM;

#pragma unroll
  for (int i = 0; i < 20; i++) {
    int flat = i * 64 + lane;
    int row = flat >> 4;
    int col = (flat & 15) * 8;
    GLD16(Kg + (size_t)row * 3072 + col, &Kt[i * 512]);
    GLD16(Vg + (size_t)row * 3072 + col, &Vt[i * 512]);
  }
  for (int i = lane; i < 16 * 128; i += 64) Vt[80 * 128 + i] = 0;  // V pad rows
  for (int i = lane; i < 159; i += 64) bias_l[i] = bias_table[i * 8 + h];
  asm volatile("s_waitcnt vmcnt(0)" ::: "memory");
  __syncthreads();

  // ---- S^T[key][q] = K * Q^T
  f32x4 sa[5][5] = {};
#pragma unroll
  for (int ks = 0; ks < 4; ks++) {
    short8_t ak[5], bq[5];
#pragma unroll
    for (int m = 0; m < 5; m++)
      ak[m] = *(const short8_t*)&Kt[(m * 16 + lo) * 128 + ks * 32 + hi * 8];
#pragma unroll
    for (int n = 0; n < 5; n++)
      bq[n] = *(const short8_t*)(Qg + (size_t)(n * 16 + lo) * 3072 + ks * 32 + hi * 8);
#pragma unroll
    for (int m = 0; m < 5; m++)
#pragma unroll
      for (int n = 0; n < 5; n++)
        sa[m][n] = __builtin_amdgcn_mfma_f32_16x16x32_bf16(ak[m], bq[n], sa[m][n], 0, 0, 0);
  }
  __syncthreads();

  // ---- softmax over keys per query column, then +bias, write P[q][key] bf16
  u16* p_lds = Kt;  // [80][104]; cols 80..95 zero (MFMA K-pad), 96..103 unused
  for (int i = lane; i < 80 * 16; i += 64) {
    int q = i >> 4, c = 80 + (i & 15);
    p_lds[q * 104 + c] = 0;
  }
  const float scale = 0.03125f;  // 1024^-0.5 (full emb scale, faithful)
#pragma unroll
  for (int n = 0; n < 5; n++) {
    float mx = -1e30f;
#pragma unroll
    for (int m = 0; m < 5; m++)
#pragma unroll
      for (int j = 0; j < 4; j++) {
        sa[m][n][j] *= scale;
        mx = fmaxf(mx, sa[m][n][j]);
      }
    mx = fmaxf(mx, __shfl_xor(mx, 16));
    mx = fmaxf(mx, __shfl_xor(mx, 32));
    float sm = 0.f;
#pragma unroll
    for (int m = 0; m < 5; m++)
#pragma unroll
      for (int j = 0; j < 4; j++) {
        float e = __expf(sa[m][n][j] - mx);
        sa[m][n][j] = e;
        sm += e;
      }
    sm += __shfl_xor(sm, 16);
    sm += __shfl_xor(sm, 32);
    float inv = 1.0f / sm;
    int q = n * 16 + lo;
#pragma unroll
    for (int m = 0; m < 5; m++)
#pragma unroll
      for (int j = 0; j < 4; j++) {
        int key = m * 16 + hi * 4 + j;
        float pv = sa[m][n][j] * inv + bias_l[q - key + 79];  // bias AFTER softmax
        p_lds[q * 104 + key] = f2bf(pv);
      }
  }
  __syncthreads();

  // ---- out[q][d] = P[q][key] * V[key][d]
#pragma unroll
  for (int half = 0; half < 2; half++) {
    f32x4 oa[5][4] = {};
#pragma unroll
    for (int ks = 0; ks < 3; ks++) {
      short8_t ap[5];
#pragma unroll
      for (int m = 0; m < 5; m++)
        ap[m] = *(const short8_t*)&p_lds[(m * 16 + lo) * 104 + ks * 32 + hi * 8];
      short8_t bv[4];
#pragma unroll
      for (int nd = 0; nd < 4; nd++) {
        int d = (half * 4 + nd) * 16 + lo;
        short8_t tt;
#pragma unroll
        for (int j = 0; j < 8; j++)
          tt[j] = (short)Vt[(ks * 32 + hi * 8 + j) * 128 + d];
        bv[nd] = tt;
      }
#pragma unroll
      for (int m = 0; m < 5; m++)
#pragma unroll
        for (int nd = 0; nd < 4; nd++)
          oa[m][nd] = __builtin_amdgcn_mfma_f32_16x16x32_bf16(ap[m], bv[nd], oa[m][nd], 0, 0, 0);
    }
#pragma unroll
    for (int m = 0; m < 5; m++)
#pragma unroll
      for (int nd = 0; nd < 4; nd++)
#pragma unroll
        for (int j = 0; j < 4; j++) {
          int q = m * 16 + hi * 4 + j;
          int d = (half * 4 + nd) * 16 + lo;
          attnout[((size_t)b * SEQ + q) * DIM + h * HDIM + d] = f2bf(oa[m][nd][j]);
        }
  }
}

// ---------------------------------------------------------------- fused LN chains
__device__ __forceinline__ void block_reduce2(float& a, float& b, float* sbuf) {
#pragma unroll
  for (int m = 1; m < 64; m <<= 1) {
    a += __shfl_xor(a, m);
    b += __shfl_xor(b, m);
  }
  int w = threadIdx.x >> 6;
  if ((threadIdx.x & 63) == 0) { sbuf[w * 2] = a; sbuf[w * 2 + 1] = b; }
  __syncthreads();
  a = sbuf[0] + sbuf[2] + sbuf[4] + sbuf[6];
  b = sbuf[1] + sbuf[3] + sbuf[5] + sbuf[7];
  __syncthreads();
}

// to_out LN on attnout (bf16), then x + out, then ln1 -> x1b (bf16)
__global__ __launch_bounds__(256) void fuse1_kernel(
    const u16* __restrict__ attnout, const float* __restrict__ x,
    const float* __restrict__ og, const float* __restrict__ ob,
    const float* __restrict__ g1, const float* __restrict__ b1,
    u16* __restrict__ x1b) {
  __shared__ float sbuf[8];
  const size_t base = (size_t)blockIdx.x * DIM;
  float a[4], r[4];
  float s0 = 0.f, s1 = 0.f;
#pragma unroll
  for (int i = 0; i < 4; i++) {
    int idx = threadIdx.x + i * 256;
    a[i] = bf2f(attnout[base + idx]);
    s0 += a[i];
    s1 += a[i] * a[i];
  }
  block_reduce2(s0, s1, sbuf);
  float mu = s0 * (1.f / DIM);
  float rstd = rsqrtf(s1 * (1.f / DIM) - mu * mu + 1e-5f);
  float t0 = 0.f, t1 = 0.f;
#pragma unroll
  for (int i = 0; i < 4; i++) {
    int idx = threadIdx.x + i * 256;
    float o = (a[i] - mu) * rstd * og[idx] + ob[idx];
    r[i] = x[base + idx] + o;
    t0 += r[i];
    t1 += r[i] * r[i];
  }
  block_reduce2(t0, t1, sbuf);
  float mu2 = t0 * (1.f / DIM);
  float rstd2 = rsqrtf(t1 * (1.f / DIM) - mu2 * mu2 + 1e-5f);
#pragma unroll
  for (int i = 0; i < 4; i++) {
    int idx = threadIdx.x + i * 256;
    x1b[base + idx] = f2bf((r[i] - mu2) * rstd2 * g1[idx] + b1[idx]);
  }
}

// out = ln2(x1 + p0 + p1 + fc2b)  (x1, p0, p1 bf16; out fp32)
__global__ __launch_bounds__(256) void fuse2_kernel(
    const u16* __restrict__ x1b, const u16* __restrict__ p0,
    const u16* __restrict__ p1, const float* __restrict__ fc2b,
    const float* __restrict__ g2, const float* __restrict__ b2,
    float* __restrict__ out) {
  __shared__ float sbuf[8];
  const size_t base = (size_t)blockIdx.x * DIM;
  float r[4];
  float s0 = 0.f, s1 = 0.f;
#pragma unroll
  for (int i = 0; i < 4; i++) {
    int idx = threadIdx.x + i * 256;
    r[i] = bf2f(x1b[base + idx]) + bf2f(p0[base + idx]) + bf2f(p1[base + idx]) +
           fc2b[idx];
    s0 += r[i];
    s1 += r[i] * r[i];
  }
  block_reduce2(s0, s1, sbuf);
  float mu = s0 * (1.f / DIM);
  float rstd = rsqrtf(s1 * (1.f / DIM) - mu * mu + 1e-5f);
#pragma unroll
  for (int i = 0; i < 4; i++) {
    int idx = threadIdx.x + i * 256;
    out[base + idx] = (r[i] - mu) * rstd * g2[idx] + b2[idx];
  }
}

// ---------------------------------------------------------------- launch
extern "C" void kernel_launch(void* const* d_in, const int* in_sizes, int n_in,
                              void* d_out, int out_size, void* d_ws, size_t ws_size,
                              hipStream_t stream) {
  const float* x        = (const float*)d_in[0];
  const float* Wq       = (const float*)d_in[1];
  const float* Wk       = (const float*)d_in[2];
  const float* Wv       = (const float*)d_in[3];
  const float* bias_tab = (const float*)d_in[4];
  const float* og       = (const float*)d_in[5];
  const float* ob       = (const float*)d_in[6];
  const float* g1       = (const float*)d_in[7];
  const float* b1       = (const float*)d_in[8];
  const float* g2       = (const float*)d_in[9];
  const float* b2       = (const float*)d_in[10];
  const float* fc1w     = (const float*)d_in[11];
  const float* fc1b     = (const float*)d_in[12];
  const float* fc2w     = (const float*)d_in[13];
  const float* fc2b     = (const float*)d_in[14];

  // --- ws layout (fixed part = 106,954,752 B), C-region sized from ws_size ---
  char* ws = (char*)d_ws;
  u16* wqkvT = (u16*)(ws + 0);                 //  6,291,456  [3072][1024]
  u16* fc1T  = (u16*)(ws + 6291456ull);        //  8,388,608  [4096][1024]
  u16* fc2T  = (u16*)(ws + 14680064ull);       //  8,388,608  [1024][4096]
  u16* pbuf  = (u16*)(ws + 23068672ull);       // 41,943,040  attnout -> fc2 p0 (bf16)
  u16* qbuf  = (u16*)(ws + 65011712ull);       // 41,943,040  xb -> x1b (bf16)
  char* cbuf = ws + 106954752ull;              // qkv chunks / (h + p1) chunks
  size_t cavail = ws_size > 106954752ull ? ws_size - 106954752ull : 0;

  // chunk counts (deterministic in ws_size); rows stay multiples of 256.
  int cb = 1;
  while (cb < 16 && (size_t)(BATCH / cb) * SEQ * 3072 * 2 > cavail) cb <<= 1;
  int cf = 1;
  while (cf < 16 && (size_t)(NTOK / cf) * (HID + DIM) * 2 > cavail) cf <<= 1;

  dim3 tb(32, 8);
  cast_bf16_kernel<<<2048, 256, 0, stream>>>(x, qbuf, NTOK * DIM / 4);
  transpose_cast_kernel<<<dim3(32, 32), tb, 0, stream>>>(Wq, wqkvT, 1024, 1024);
  transpose_cast_kernel<<<dim3(32, 32), tb, 0, stream>>>(Wk, wqkvT + 1024 * 1024, 1024, 1024);
  transpose_cast_kernel<<<dim3(32, 32), tb, 0, stream>>>(Wv, wqkvT + 2 * 1024 * 1024, 1024, 1024);
  transpose_cast_kernel<<<dim3(128, 32), tb, 0, stream>>>(fc1w, fc1T, 1024, 4096);
  transpose_cast_kernel<<<dim3(32, 128), tb, 0, stream>>>(fc2w, fc2T, 4096, 1024);

  // QKV projection + attention, chunked over batches
  {
    const int nb = BATCH / cb;                 // batches per chunk
    const int rows = nb * SEQ;                 // multiple of 256 for cb<=16
    u16* qkvc = (u16*)cbuf;
    const int ntm = rows / 256;
    const int nwg = ntm * 12;
    for (int c = 0; c < cb; ++c) {
      const u16* xb_c = qbuf + (size_t)c * rows * DIM;
      gemm4q<0><<<nwg, 512, 0, stream>>>(xb_c, wqkvT, nullptr, qkvc, qkvc,
                                         rows, 3072, 1024, 1024, 12, ntm);
      attn_kernel<<<nb * HEADS, 64, 0, stream>>>(
          qkvc, bias_tab, pbuf + (size_t)c * rows * DIM);
    }
  }

  fuse1_kernel<<<NTOK, 256, 0, stream>>>(pbuf, x, og, ob, g1, b1, qbuf);

  // FFN, chunked over token rows; fc2 split-K=2 (p0 -> pbuf, p1 -> cbuf tail),
  // bias + reduction folded into fuse2 (runs per chunk).
  {
    const int rows = NTOK / cf;                // multiple of 256 for cf<=16
    u16* hc  = (u16*)cbuf;
    u16* p1c = (u16*)(cbuf + (size_t)rows * HID * 2);
    const int ntm = rows / 256;
    for (int c = 0; c < cf; ++c) {
      const size_t off = (size_t)c * rows * DIM;
      gemm4q<1><<<ntm * 16, 512, 0, stream>>>(qbuf + off, fc1T, fc1b, hc, hc,
                                              rows, HID, 1024, 1024, 16, ntm);
      gemm4q<0><<<ntm * 4 * 2, 512, 0, stream>>>(hc, fc2T, nullptr,
                                                 pbuf + off, p1c,
                                                 rows, 1024, 2048, 4096, 4, ntm);
      fuse2_kernel<<<rows, 256, 0, stream>>>(qbuf + off, pbuf + off, p1c, fc2b,
                                             g2, b2, (float*)d_out + off);
    }
  }
}

// Round 13
// 746.875 us; speedup vs baseline: 1.0965x; 1.0965x over previous
//
// Round 13: best-known base (R8, 759us) + (a) remove explicit lgkmcnt(0) drains
// (compiler emits fine-grained counted waits for compiler-visible ds_reads),
// (b) fc2 split-K=2 with reduction folded into fuse2 (tail fix). All else R8.
#include <hip/hip_runtime.h>
#include <stdint.h>

#define BATCH 256
#define SEQ   80
#define DIM   1024
#define HEADS 8
#define HDIM  128
#define HID   4096
#define NTOK  (BATCH * SEQ)   // 20480

typedef unsigned short u16;
using short8_t = __attribute__((ext_vector_type(8))) short;   // 8 bf16 (4 VGPRs)
using f32x4    = __attribute__((ext_vector_type(4))) float;

__device__ __forceinline__ u16 f2bf(float f) {
  unsigned u = __float_as_uint(f);
  u += 0x7fffu + ((u >> 16) & 1u);   // RNE; inputs are finite
  return (u16)(u >> 16);
}
__device__ __forceinline__ float bf2f(u16 u) {
  return __uint_as_float(((unsigned)u) << 16);
}

__device__ __forceinline__ float gelu_exact(float v) {
  return 0.5f * v * (1.0f + erff(v * 0.70710678118654752f));
}

// async global->LDS, 16B per lane; lds dest = base + lane*16 (base wave-uniform)
#define GLD16(gp, lp)                                                   \
  __builtin_amdgcn_global_load_lds(                                     \
      (__attribute__((address_space(1))) void*)(void*)(gp),             \
      (__attribute__((address_space(3))) void*)(void*)(lp), 16, 0, 0)

// ---------------------------------------------------------------- casts
__global__ __launch_bounds__(256) void cast_bf16_kernel(
    const float* __restrict__ in, u16* __restrict__ out, int n4) {
  int i = blockIdx.x * 256 + threadIdx.x;
  int stride = gridDim.x * 256;
  for (; i < n4; i += stride) {
    float4 v = ((const float4*)in)[i];
    uint2 o;
    o.x = (unsigned)f2bf(v.x) | ((unsigned)f2bf(v.y) << 16);
    o.y = (unsigned)f2bf(v.z) | ((unsigned)f2bf(v.w) << 16);
    ((uint2*)out)[i] = o;
  }
}

// in: R x C fp32 row-major -> out: C x R bf16 row-major  (R,C multiples of 32)
__global__ __launch_bounds__(256) void transpose_cast_kernel(
    const float* __restrict__ in, u16* __restrict__ out, int R, int C) {
  __shared__ float tile[32][33];
  int c0 = blockIdx.x * 32, r0 = blockIdx.y * 32;
  for (int k = 0; k < 4; k++) {
    int i = threadIdx.y + k * 8;
    tile[i][threadIdx.x] = in[(size_t)(r0 + i) * C + c0 + threadIdx.x];
  }
  __syncthreads();
  for (int k = 0; k < 4; k++) {
    int i = threadIdx.y + k * 8;
    out[(size_t)(c0 + i) * R + r0 + threadIdx.x] = f2bf(tile[threadIdx.x][i]);
  }
}

// ---------------------------------------------------------------- pipelined 8-phase GEMM
// R8's exact schedule (759us best) + split-K + no explicit lgkmcnt(0) (compiler
// emits counted waits for compiler-visible ds_reads -> first MFMA starts earlier).
// C[M,N] = A[M,Ks-slice] * Bt[N,Ks-slice]^T, bf16 out. 256x256 tile, 8 waves (2Mx4N),
// per-wave 128x64 = acc[8][4] of 16x16 frags, 16x16x32 MFMA. Tiles BK=64 (k-halves).
// LDS: 8 regions x 8192 u16 (region = buf*4 + mat*2 + kh) = 128 KiB.
// Stage schedule: P0: A[1,k1]@t1-CURRENT (prologue skips it); P1..P4: B0k0,A0k0,
// B0k1,A0k1 @t0+2; P5..P7: B1k0,A1k0,B1k1 @t1+2.
// Counted waits VM(8)@P0,P2,P4 and VM(10)@P7 (R8's verified FIFO ledger).
// Peeled last iteration: VM(8)@P0, VM(4)@P2, VM(0)@P4.
// Split-K: kp = swz/(ntn*ntm); reads K-cols [kp*Keff,(kp+1)*Keff), writes
// outp (kp=0) / outp1 (kp=1). EPI: 0 plain; 1 +bias GELU; 2 +bias. Keff%128==0.
template <int EPI>
__global__ __launch_bounds__(512, 2) void gemm8s(
    const u16* __restrict__ A, const u16* __restrict__ Bt,
    const float* __restrict__ bias, u16* __restrict__ outp, u16* __restrict__ outp1,
    int M, int N, int Keff, int Ks, int ntn, int ntm) {
  __shared__ __align__(16) u16 lds[65536];   // 8 x 8192 u16 = 128 KiB

  const int tid = threadIdx.x;
  const int lane = tid & 63, wave = tid >> 6;
  const int wm = wave >> 2, wn = wave & 3;
  const int lo = lane & 15, hi = lane >> 4;

  // bijective XCD swizzle (m204 variant)
  const int nwg = gridDim.x;
  int q8 = nwg >> 3, r8 = nwg & 7;
  int xcd = blockIdx.x & 7, off = blockIdx.x >> 3;
  int swz = (xcd < r8 ? xcd * (q8 + 1) : r8 * (q8 + 1) + (xcd - r8) * q8) + off;
  const int per = ntn * ntm;
  const int kp = swz / per, rem = swz % per;
  const int bn = rem % ntn, bm = rem / ntn;
  const size_t arow0 = (size_t)bm * 256, bcol0 = (size_t)bn * 256;
  const int kbase = kp * Keff;

  // staging: thread covers granules {tid, 512+tid} of each region (1024 x 16B).
  const int srow = tid >> 2;
  const int slb  = (tid & 3) ^ ((srow >> 1) & 3);
  const u16* sA = A + (arow0 + srow) * (size_t)Ks + kbase + slb * 8;
  const u16* sB = Bt + (bcol0 + srow) * (size_t)Ks + kbase + slb * 8;
  const size_t sstep = 128 * (size_t)Ks;

  // frag read bases (u16); swizzled granule, m-independent ((row>>1)&3 stable).
  const int arow = wm * 128 + lo;
  const int brow = wn * 64 + lo;
  const int aoff = arow * 32 + (hi ^ ((arow >> 1) & 3)) * 8;
  const int boff = brow * 32 + (hi ^ ((brow >> 1) & 3)) * 8;

  f32x4 acc[8][4] = {};
  const int NT = Keff >> 6;   // BK=64 tiles
  const int NI = NT >> 1;     // iterations (2 tiles each)

#define STG(mat, buf, kh, t)                                                  \
  do {                                                                        \
    const u16* s_ = ((mat) ? sB : sA) + (size_t)(t) * 64 + (kh) * 32;         \
    u16* d_ = lds + ((((buf) << 2) | ((mat) << 1) | (kh)) << 13) + wave * 512;\
    GLD16(s_, d_);                                                            \
    GLD16(s_ + sstep, d_ + 4096);                                             \
  } while (0)

#define RD_A(buf, kh, mh, dst)                                                \
  _Pragma("unroll") for (int mi = 0; mi < 4; ++mi)                            \
      dst[mi] = *(const short8_t*)&lds[((((buf) << 2) | (kh)) << 13) + aoff + \
                                       ((mh) * 4 + mi) * 512];

#define RD_B(buf, kh, dst)                                                    \
  _Pragma("unroll") for (int ni = 0; ni < 4; ++ni)                            \
      dst[ni] = *(const short8_t*)&lds[((((buf) << 2) | 2 | (kh)) << 13) +    \
                                       boff + ni * 512];

#define MFMA16(mh, a_, b_)                                                    \
  __builtin_amdgcn_s_setprio(1);                                              \
  _Pragma("unroll") for (int mi = 0; mi < 4; ++mi)                            \
  _Pragma("unroll") for (int ni = 0; ni < 4; ++ni)                            \
      acc[(mh) * 4 + mi][ni] = __builtin_amdgcn_mfma_f32_16x16x32_bf16(       \
          a_[mi], b_[ni], acc[(mh) * 4 + mi][ni], 0, 0, 0);                   \
  __builtin_amdgcn_s_setprio(0);

#define BAR()   asm volatile("s_barrier" ::: "memory")
#define VM(n)   asm volatile("s_waitcnt vmcnt(" #n ")" ::: "memory")

  // prologue: stage tiles 0,1 EXCEPT A[1,k1] (staged at P0 each iter @ its t1)
  STG(0, 0, 0, 0); STG(1, 0, 0, 0); STG(0, 0, 1, 0); STG(1, 0, 1, 0);
  STG(0, 1, 0, 1); STG(1, 1, 0, 1); STG(1, 1, 1, 1);
  asm volatile("s_waitcnt vmcnt(0)" ::: "memory");
  BAR();

  short8_t aR0[4], aR1[4], bR0[4], bR1[4];

  for (int i = 0; i < NI - 1; ++i) {
    const int t0 = 2 * i, t1 = 2 * i + 1;
    // P0 (serial head: own frags, MFMA, preload P1) — waits are compiler-counted
    RD_A(0, 0, 0, aR0); RD_B(0, 0, bR0);
    MFMA16(0, aR0, bR0);
    RD_A(0, 0, 1, aR1);
    STG(0, 1, 1, t1);               // A[1,k1] @ CURRENT t1
    VM(8); BAR();
    // P1
    MFMA16(1, aR1, bR0);
    RD_A(0, 1, 0, aR0); RD_B(0, 1, bR1);
    STG(1, 0, 0, t0 + 2);           // B[0,k0]
    BAR();
    // P2
    MFMA16(0, aR0, bR1);
    RD_A(0, 1, 1, aR1);
    STG(0, 0, 0, t0 + 2);           // A[0,k0]
    VM(8); BAR();
    // P3
    MFMA16(1, aR1, bR1);
    RD_A(1, 0, 0, aR0); RD_B(1, 0, bR0);
    STG(1, 0, 1, t0 + 2);           // B[0,k1]
    BAR();
    // P4
    MFMA16(0, aR0, bR0);
    RD_A(1, 0, 1, aR1);
    STG(0, 0, 1, t0 + 2);           // A[0,k1]
    VM(8); BAR();
    // P5
    MFMA16(1, aR1, bR0);
    RD_A(1, 1, 0, aR0); RD_B(1, 1, bR1);
    STG(1, 1, 0, t1 + 2);           // B[1,k0]
    BAR();
    // P6
    MFMA16(0, aR0, bR1);
    RD_A(1, 1, 1, aR1);
    STG(0, 1, 0, t1 + 2);           // A[1,k0]
    BAR();
    // P7
    MFMA16(1, aR1, bR1);
    STG(1, 1, 1, t1 + 2);           // B[1,k1]
    VM(10); BAR();
  }

  // ---- peeled last iteration (no prefetch stages; deeper counted waits)
  {
    const int t1 = NT - 1;
    // P0
    RD_A(0, 0, 0, aR0); RD_B(0, 0, bR0);
    MFMA16(0, aR0, bR0);
    RD_A(0, 0, 1, aR1);
    STG(0, 1, 1, t1);               // A[1,k1] @ t1 (last tile)
    VM(8); BAR();
    // P1
    MFMA16(1, aR1, bR0);
    RD_A(0, 1, 0, aR0); RD_B(0, 1, bR1);
    BAR();
    // P2
    MFMA16(0, aR0, bR1);
    RD_A(0, 1, 1, aR1);
    VM(4); BAR();
    // P3
    MFMA16(1, aR1, bR1);
    RD_A(1, 0, 0, aR0); RD_B(1, 0, bR0);
    BAR();
    // P4
    MFMA16(0, aR0, bR0);
    RD_A(1, 0, 1, aR1);
    VM(0); BAR();
    // P5
    MFMA16(1, aR1, bR0);
    RD_A(1, 1, 0, aR0); RD_B(1, 1, bR1);
    BAR();
    // P6
    MFMA16(0, aR0, bR1);
    RD_A(1, 1, 1, aR1);
    BAR();
    // P7
    MFMA16(1, aR1, bR1);
    BAR();
  }
#undef STG
#undef RD_A
#undef RD_B
#undef MFMA16

  asm volatile("s_waitcnt vmcnt(0)" ::: "memory");
  __syncthreads();

  // epilogue: acc -> LDS [256][256] u16 tile -> coalesced full-line stores
  u16* ct = lds;
#pragma unroll
  for (int n = 0; n < 4; ++n) {
    int col = wn * 64 + n * 16 + lo;
    float bv = 0.f;
    if constexpr (EPI != 0) bv = bias[bcol0 + col];
#pragma unroll
    for (int m = 0; m < 8; ++m) {
#pragma unroll
      for (int j = 0; j < 4; ++j) {
        int row = wm * 128 + m * 16 + hi * 4 + j;
        float v = acc[m][n][j] + bv;
        if constexpr (EPI == 1) v = gelu_exact(v);
        ct[row * 256 + col] = f2bf(v);
      }
    }
  }
  __syncthreads();
  u16* op = (kp ? outp1 : outp) + arow0 * (size_t)N + bcol0;
#pragma unroll
  for (int i = 0; i < 16; ++i) {
    int c = i * 512 + tid;
    int row = c >> 5, o2 = (c & 31) * 8;
    *(short8_t*)(op + (size_t)row * N + o2) = *(const short8_t*)&ct[row * 256 + o2];
  }
}

// ---------------------------------------------------------------- attention
// One wave per (local b, h). QKV chunk: [nb*80][3072] bf16 (Q|K|V, head h at h*128).
__global__ __launch_bounds__(64) void attn_kernel(
    const u16* __restrict__ QKV, const float* __restrict__ bias_table,
    u16* __restrict__ attnout) {
  __shared__ __align__(16) u16 Kt[80 * 128];   // [key][d]; reused as P [80][104]
  __shared__ __align__(16) u16 Vt[96 * 128];   // [key][d], rows 80..95 zeroed
  __shared__ float bias_l[159];

  const int bh = blockIdx.x;
  const int b = bh >> 3, h = bh & 7;
  const int lane = threadIdx.x, lo = lane & 15, hi = lane >> 4;
  const size_t tokbase = (size_t)b * SEQ * 3072;
  const u16* Qg = QKV + tokbase + h * HDIM;
  const u16* Kg = QKV + tokbase + 1024 + h * HDIM;
  const u16* Vg = QKV + tokbase + 2048 + h * HDIM;

#pragma unroll
  for (int i = 0; i < 20; i++) {
    int flat = i * 64 + lane;
    int row = flat >> 4;
    int col = (flat & 15) * 8;
    GLD16(Kg + (size_t)row * 3072 + col, &Kt[i * 512]);
    GLD16(Vg + (size_t)row * 3072 + col, &Vt[i * 512]);
  }
  for (int i = lane; i < 16 * 128; i += 64) Vt[80 * 128 + i] = 0;  // V pad rows
  for (int i = lane; i < 159; i += 64) bias_l[i] = bias_table[i * 8 + h];
  asm volatile("s_waitcnt vmcnt(0)" ::: "memory");
  __syncthreads();

  // ---- S^T[key][q] = K * Q^T
  f32x4 sa[5][5] = {};
#pragma unroll
  for (int ks = 0; ks < 4; ks++) {
    short8_t ak[5], bq[5];
#pragma unroll
    for (int m = 0; m < 5; m++)
      ak[m] = *(const short8_t*)&Kt[(m * 16 + lo) * 128 + ks * 32 + hi * 8];
#pragma unroll
    for (int n = 0; n < 5; n++)
      bq[n] = *(const short8_t*)(Qg + (size_t)(n * 16 + lo) * 3072 + ks * 32 + hi * 8);
#pragma unroll
    for (int m = 0; m < 5; m++)
#pragma unroll
      for (int n = 0; n < 5; n++)
        sa[m][n] = __builtin_amdgcn_mfma_f32_16x16x32_bf16(ak[m], bq[n], sa[m][n], 0, 0, 0);
  }
  __syncthreads();

  // ---- softmax over keys per query column, then +bias, write P[q][key] bf16
  u16* p_lds = Kt;  // [80][104]; cols 80..95 zero (MFMA K-pad), 96..103 unused
  for (int i = lane; i < 80 * 16; i += 64) {
    int q = i >> 4, c = 80 + (i & 15);
    p_lds[q * 104 + c] = 0;
  }
  const float scale = 0.03125f;  // 1024^-0.5 (full emb scale, faithful)
#pragma unroll
  for (int n = 0; n < 5; n++) {
    float mx = -1e30f;
#pragma unroll
    for (int m = 0; m < 5; m++)
#pragma unroll
      for (int j = 0; j < 4; j++) {
        sa[m][n][j] *= scale;
        mx = fmaxf(mx, sa[m][n][j]);
      }
    mx = fmaxf(mx, __shfl_xor(mx, 16));
    mx = fmaxf(mx, __shfl_xor(mx, 32));
    float sm = 0.f;
#pragma unroll
    for (int m = 0; m < 5; m++)
#pragma unroll
      for (int j = 0; j < 4; j++) {
        float e = __expf(sa[m][n][j] - mx);
        sa[m][n][j] = e;
        sm += e;
      }
    sm += __shfl_xor(sm, 16);
    sm += __shfl_xor(sm, 32);
    float inv = 1.0f / sm;
    int q = n * 16 + lo;
#pragma unroll
    for (int m = 0; m < 5; m++)
#pragma unroll
      for (int j = 0; j < 4; j++) {
        int key = m * 16 + hi * 4 + j;
        float pv = sa[m][n][j] * inv + bias_l[q - key + 79];  // bias AFTER softmax
        p_lds[q * 104 + key] = f2bf(pv);
      }
  }
  __syncthreads();

  // ---- out[q][d] = P[q][key] * V[key][d]
#pragma unroll
  for (int half = 0; half < 2; half++) {
    f32x4 oa[5][4] = {};
#pragma unroll
    for (int ks = 0; ks < 3; ks++) {
      short8_t ap[5];
#pragma unroll
      for (int m = 0; m < 5; m++)
        ap[m] = *(const short8_t*)&p_lds[(m * 16 + lo) * 104 + ks * 32 + hi * 8];
      short8_t bv[4];
#pragma unroll
      for (int nd = 0; nd < 4; nd++) {
        int d = (half * 4 + nd) * 16 + lo;
        short8_t tt;
#pragma unroll
        for (int j = 0; j < 8; j++)
          tt[j] = (short)Vt[(ks * 32 + hi * 8 + j) * 128 + d];
        bv[nd] = tt;
      }
#pragma unroll
      for (int m = 0; m < 5; m++)
#pragma unroll
        for (int nd = 0; nd < 4; nd++)
          oa[m][nd] = __builtin_amdgcn_mfma_f32_16x16x32_bf16(ap[m], bv[nd], oa[m][nd], 0, 0, 0);
    }
#pragma unroll
    for (int m = 0; m < 5; m++)
#pragma unroll
      for (int nd = 0; nd < 4; nd++)
#pragma unroll
        for (int j = 0; j < 4; j++) {
          int q = m * 16 + hi * 4 + j;
          int d = (half * 4 + nd) * 16 + lo;
          attnout[((size_t)b * SEQ + q) * DIM + h * HDIM + d] = f2bf(oa[m][nd][j]);
        }
  }
}

// ---------------------------------------------------------------- fused LN chains
__device__ __forceinline__ void block_reduce2(float& a, float& b, float* sbuf) {
#pragma unroll
  for (int m = 1; m < 64; m <<= 1) {
    a += __shfl_xor(a, m);
    b += __shfl_xor(b, m);
  }
  int w = threadIdx.x >> 6;
  if ((threadIdx.x & 63) == 0) { sbuf[w * 2] = a; sbuf[w * 2 + 1] = b; }
  __syncthreads();
  a = sbuf[0] + sbuf[2] + sbuf[4] + sbuf[6];
  b = sbuf[1] + sbuf[3] + sbuf[5] + sbuf[7];
  __syncthreads();
}

// to_out LN on attnout (bf16), then x + out, then ln1 -> x1b (bf16)
__global__ __launch_bounds__(256) void fuse1_kernel(
    const u16* __restrict__ attnout, const float* __restrict__ x,
    const float* __restrict__ og, const float* __restrict__ ob,
    const float* __restrict__ g1, const float* __restrict__ b1,
    u16* __restrict__ x1b) {
  __shared__ float sbuf[8];
  const size_t base = (size_t)blockIdx.x * DIM;
  float a[4], r[4];
  float s0 = 0.f, s1 = 0.f;
#pragma unroll
  for (int i = 0; i < 4; i++) {
    int idx = threadIdx.x + i * 256;
    a[i] = bf2f(attnout[base + idx]);
    s0 += a[i];
    s1 += a[i] * a[i];
  }
  block_reduce2(s0, s1, sbuf);
  float mu = s0 * (1.f / DIM);
  float rstd = rsqrtf(s1 * (1.f / DIM) - mu * mu + 1e-5f);
  float t0 = 0.f, t1 = 0.f;
#pragma unroll
  for (int i = 0; i < 4; i++) {
    int idx = threadIdx.x + i * 256;
    float o = (a[i] - mu) * rstd * og[idx] + ob[idx];
    r[i] = x[base + idx] + o;
    t0 += r[i];
    t1 += r[i] * r[i];
  }
  block_reduce2(t0, t1, sbuf);
  float mu2 = t0 * (1.f / DIM);
  float rstd2 = rsqrtf(t1 * (1.f / DIM) - mu2 * mu2 + 1e-5f);
#pragma unroll
  for (int i = 0; i < 4; i++) {
    int idx = threadIdx.x + i * 256;
    x1b[base + idx] = f2bf((r[i] - mu2) * rstd2 * g1[idx] + b1[idx]);
  }
}

// out = ln2(x1 + p0 + p1 + fc2b)  (x1, p0, p1 bf16; out fp32)
__global__ __launch_bounds__(256) void fuse2_kernel(
    const u16* __restrict__ x1b, const u16* __restrict__ p0,
    const u16* __restrict__ p1, const float* __restrict__ fc2b,
    const float* __restrict__ g2, const float* __restrict__ b2,
    float* __restrict__ out) {
  __shared__ float sbuf[8];
  const size_t base = (size_t)blockIdx.x * DIM;
  float r[4];
  float s0 = 0.f, s1 = 0.f;
#pragma unroll
  for (int i = 0; i < 4; i++) {
    int idx = threadIdx.x + i * 256;
    r[i] = bf2f(x1b[base + idx]) + bf2f(p0[base + idx]) + bf2f(p1[base + idx]) +
           fc2b[idx];
    s0 += r[i];
    s1 += r[i] * r[i];
  }
  block_reduce2(s0, s1, sbuf);
  float mu = s0 * (1.f / DIM);
  float rstd = rsqrtf(s1 * (1.f / DIM) - mu * mu + 1e-5f);
#pragma unroll
  for (int i = 0; i < 4; i++) {
    int idx = threadIdx.x + i * 256;
    out[base + idx] = (r[i] - mu) * rstd * g2[idx] + b2[idx];
  }
}

// ---------------------------------------------------------------- launch
extern "C" void kernel_launch(void* const* d_in, const int* in_sizes, int n_in,
                              void* d_out, int out_size, void* d_ws, size_t ws_size,
                              hipStream_t stream) {
  const float* x        = (const float*)d_in[0];
  const float* Wq       = (const float*)d_in[1];
  const float* Wk       = (const float*)d_in[2];
  const float* Wv       = (const float*)d_in[3];
  const float* bias_tab = (const float*)d_in[4];
  const float* og       = (const float*)d_in[5];
  const float* ob       = (const float*)d_in[6];
  const float* g1       = (const float*)d_in[7];
  const float* b1       = (const float*)d_in[8];
  const float* g2       = (const float*)d_in[9];
  const float* b2       = (const float*)d_in[10];
  const float* fc1w     = (const float*)d_in[11];
  const float* fc1b     = (const float*)d_in[12];
  const float* fc2w     = (const float*)d_in[13];
  const float* fc2b     = (const float*)d_in[14];

  // --- ws layout (fixed part = 106,954,752 B), C-region sized from ws_size ---
  char* ws = (char*)d_ws;
  u16* wqkvT = (u16*)(ws + 0);                 //  6,291,456  [3072][1024]
  u16* fc1T  = (u16*)(ws + 6291456ull);        //  8,388,608  [4096][1024]
  u16* fc2T  = (u16*)(ws + 14680064ull);       //  8,388,608  [1024][4096]
  u16* pbuf  = (u16*)(ws + 23068672ull);       // 41,943,040  attnout -> fc2 p0 (bf16)
  u16* qbuf  = (u16*)(ws + 65011712ull);       // 41,943,040  xb -> x1b (bf16)
  char* cbuf = ws + 106954752ull;              // qkv chunks / (h + p1) chunks
  size_t cavail = ws_size > 106954752ull ? ws_size - 106954752ull : 0;

  // chunk counts (deterministic in ws_size); rows stay multiples of 256.
  int cb = 1;
  while (cb < 16 && (size_t)(BATCH / cb) * SEQ * 3072 * 2 > cavail) cb <<= 1;
  int cf = 1;
  while (cf < 16 && (size_t)(NTOK / cf) * (HID + DIM) * 2 > cavail) cf <<= 1;

  dim3 tb(32, 8);
  cast_bf16_kernel<<<2048, 256, 0, stream>>>(x, qbuf, NTOK * DIM / 4);
  transpose_cast_kernel<<<dim3(32, 32), tb, 0, stream>>>(Wq, wqkvT, 1024, 1024);
  transpose_cast_kernel<<<dim3(32, 32), tb, 0, stream>>>(Wk, wqkvT + 1024 * 1024, 1024, 1024);
  transpose_cast_kernel<<<dim3(32, 32), tb, 0, stream>>>(Wv, wqkvT + 2 * 1024 * 1024, 1024, 1024);
  transpose_cast_kernel<<<dim3(128, 32), tb, 0, stream>>>(fc1w, fc1T, 1024, 4096);
  transpose_cast_kernel<<<dim3(32, 128), tb, 0, stream>>>(fc2w, fc2T, 4096, 1024);

  // QKV projection + attention, chunked over batches
  {
    const int nb = BATCH / cb;                 // batches per chunk
    const int rows = nb * SEQ;                 // multiple of 256 for cb<=16
    u16* qkvc = (u16*)cbuf;
    const int ntm = rows / 256;
    const int nwg = ntm * 12;
    for (int c = 0; c < cb; ++c) {
      const u16* xb_c = qbuf + (size_t)c * rows * DIM;
      gemm8s<0><<<nwg, 512, 0, stream>>>(xb_c, wqkvT, nullptr, qkvc, qkvc,
                                         rows, 3072, 1024, 1024, 12, ntm);
      attn_kernel<<<nb * HEADS, 64, 0, stream>>>(
          qkvc, bias_tab, pbuf + (size_t)c * rows * DIM);
    }
  }

  fuse1_kernel<<<NTOK, 256, 0, stream>>>(pbuf, x, og, ob, g1, b1, qbuf);

  // FFN, chunked over token rows; fc2 split-K=2 (p0 -> pbuf, p1 -> cbuf tail),
  // bias + reduction folded into fuse2 (runs per chunk).
  {
    const int rows = NTOK / cf;                // multiple of 256 for cf<=16
    u16* hc  = (u16*)cbuf;
    u16* p1c = (u16*)(cbuf + (size_t)rows * HID * 2);
    const int ntm = rows / 256;
    for (int c = 0; c < cf; ++c) {
      const size_t off = (size_t)c * rows * DIM;
      gemm8s<1><<<ntm * 16, 512, 0, stream>>>(qbuf + off, fc1T, fc1b, hc, hc,
                                              rows, HID, 1024, 1024, 16, ntm);
      gemm8s<0><<<ntm * 4 * 2, 512, 0, stream>>>(hc, fc2T, nullptr,
                                                 pbuf + off, p1c,
                                                 rows, 1024, 2048, 4096, 4, ntm);
      fuse2_kernel<<<rows, 256, 0, stream>>>(qbuf + off, pbuf + off, p1c, fc2b,
                                             g2, b2, (float*)d_out + off);
    }
  }
}